// Round 7
// baseline (836.750 us; speedup 1.0000x reference)
//
#include <hip/hip_runtime.h>
#include <hip/hip_bf16.h>

#define DD 256   // feature dim
#define HH 128   // hidden dim

// ---------------------------------------------------------------------------
// CSR build, step 1: degree histogram. One thread per edge.
// int32/int64 probe: int64 values < 2^31 have all-zero odd 32-bit words.
// ---------------------------------------------------------------------------
__global__ __launch_bounds__(256) void hogrl_hist(
    const int* __restrict__ ei, int* __restrict__ deg_i, int E, int N)
{
    __shared__ int sh_is64;
    if (threadIdx.x == 0) {
        int probe = 0;
#pragma unroll
        for (int k = 1; k < 32; k += 2) probe |= ei[k];
        sh_is64 = (probe == 0);
    }
    __syncthreads();
    const int e = blockIdx.x * 256 + threadIdx.x;
    if (e >= E) return;
    int r;
    if (sh_is64) r = (int)((const long long*)ei)[e];
    else         r = ei[e];
    if ((unsigned)r < (unsigned)N) atomicAdd(&deg_i[r], 1);
}

// ---------------------------------------------------------------------------
// CSR build, step 2: exclusive prefix sum (single block, 1024 threads).
// Also pre-fills cursor[] with the offsets so fill can atomically bump it
// for an absolute slot (no extra offs read).
// ---------------------------------------------------------------------------
__global__ __launch_bounds__(1024) void hogrl_scan(
    const int* __restrict__ deg_i, int* __restrict__ offs,
    int* __restrict__ cursor, int N)
{
    __shared__ int s[1024];
    const int t = threadIdx.x;
    const int chunk = (N + 1023) / 1024;
    const int lo = min(t * chunk, N), hi = min(lo + chunk, N);
    int sum = 0;
    for (int i = lo; i < hi; ++i) sum += deg_i[i];
    s[t] = sum;
    __syncthreads();
    for (int off = 1; off < 1024; off <<= 1) {
        const int v = (t >= off) ? s[t - off] : 0;
        __syncthreads();
        s[t] += v;
        __syncthreads();
    }
    int run = (t == 0) ? 0 : s[t - 1];
    for (int i = lo; i < hi; ++i) {
        offs[i] = run;
        cursor[i] = run;
        run += deg_i[i];
    }
    if (t == 1023) offs[N] = s[1023];
}

// ---------------------------------------------------------------------------
// CSR build, step 3: fill column lists. cursor holds absolute slots.
// ---------------------------------------------------------------------------
__global__ __launch_bounds__(256) void hogrl_fill(
    const int* __restrict__ ei, int* __restrict__ cursor,
    int* __restrict__ csr, int E, int N)
{
    __shared__ int sh_is64;
    if (threadIdx.x == 0) {
        int probe = 0;
#pragma unroll
        for (int k = 1; k < 32; k += 2) probe |= ei[k];
        sh_is64 = (probe == 0);
    }
    __syncthreads();
    const int e = blockIdx.x * 256 + threadIdx.x;
    if (e >= E) return;
    int r, c;
    if (sh_is64) {
        const long long* e64 = (const long long*)ei;
        r = (int)e64[e];
        c = (int)e64[(size_t)E + e];
    } else {
        r = ei[e];
        c = ei[E + e];
    }
    if ((unsigned)r >= (unsigned)N || (unsigned)c >= (unsigned)N) return;
    const int slot = atomicAdd(&cursor[r], 1);
    csr[slot] = c;
}

// ---------------------------------------------------------------------------
// One-time weight transpose so GEMM threads read their column contiguously.
//   WT [512][256]: col j of [W_ord0|W_ord1|W_ord2|W_orig]
//   W1T[128][256]: col j of W1
// ---------------------------------------------------------------------------
__global__ __launch_bounds__(256) void hogrl_wprep(
    const float* __restrict__ W_ord, const float* __restrict__ W_orig,
    const float* __restrict__ W1,
    float* __restrict__ WT, float* __restrict__ W1T)
{
    const int b = blockIdx.x;
    const int t = threadIdx.x;
    if (b < 512) {
        float v;
        if (b < 384) v = W_ord[(size_t)(b >> 7) * DD * HH + (size_t)t * HH + (b & 127)];
        else         v = W_orig[(size_t)t * HH + (b - 384)];
        WT[(size_t)b * DD + t] = v;
    } else {
        const int j = b - 512;  // 0..127
        W1T[(size_t)j * 256 + t] = W1[(size_t)t * HH + j];
    }
}

// ---------------------------------------------------------------------------
// Fused node kernel: CSR gather (registers) + GEMM(transposed W) + gating +
// MLP + output. 8 nodes per 256-thread block; each wave gathers 2 nodes.
// ---------------------------------------------------------------------------
__global__ __launch_bounds__(256) void hogrl_node(
    const int* __restrict__ offs, const int* __restrict__ csr,
    const float* __restrict__ x,
    const float* __restrict__ WT, const float* __restrict__ b_ord,
    const float* __restrict__ W_gate, const float* __restrict__ b_gate,
    const float* __restrict__ b_orig,
    const float* __restrict__ W1T, const float* __restrict__ b1,
    const float* __restrict__ W2, const float* __restrict__ b2,
    const float* __restrict__ gamma_p,
    float* __restrict__ out, int N)
{
    __shared__ float xa[8][DD];      // 8 KiB  aggregated features
    __shared__ float yl[8][512];     // 16 KiB
    __shared__ float zl[8][2 * HH];  // 8 KiB
    __shared__ float h1l[8][HH];     // 4 KiB
    __shared__ float dgs[8];

    const int t  = threadIdx.x;
    const int n0 = blockIdx.x * 8;
    const int lane = t & 63;
    const int wv = t >> 6;

    // ---- CSR gather: wave wv accumulates nodes wv*2, wv*2+1 in registers --
#pragma unroll
    for (int nn = 0; nn < 2; ++nn) {
        const int k = wv * 2 + nn;
        const int node = n0 + k;
        float4 acc = make_float4(0.f, 0.f, 0.f, 0.f);
        int degn = 0;
        if (node < N) {
            const int s0 = offs[node], e0 = offs[node + 1];
            degn = e0 - s0;
            int i = s0;
            for (; i + 4 <= e0; i += 4) {
                const int c0 = csr[i + 0], c1 = csr[i + 1];
                const int c2 = csr[i + 2], c3 = csr[i + 3];
                const float4 v0 = *reinterpret_cast<const float4*>(x + (size_t)c0 * DD + lane * 4);
                const float4 v1 = *reinterpret_cast<const float4*>(x + (size_t)c1 * DD + lane * 4);
                const float4 v2 = *reinterpret_cast<const float4*>(x + (size_t)c2 * DD + lane * 4);
                const float4 v3 = *reinterpret_cast<const float4*>(x + (size_t)c3 * DD + lane * 4);
                acc.x += v0.x + v1.x + v2.x + v3.x;
                acc.y += v0.y + v1.y + v2.y + v3.y;
                acc.z += v0.z + v1.z + v2.z + v3.z;
                acc.w += v0.w + v1.w + v2.w + v3.w;
            }
            for (; i < e0; ++i) {
                const int c = csr[i];
                const float4 v = *reinterpret_cast<const float4*>(x + (size_t)c * DD + lane * 4);
                acc.x += v.x; acc.y += v.y; acc.z += v.z; acc.w += v.w;
            }
        }
        *reinterpret_cast<float4*>(&xa[k][lane * 4]) = acc;
        if (lane == 0) dgs[k] = (float)degn;
    }
    __syncthreads();

    // ---- fused 256x512 GEMM, transposed weights (contiguous per-thread) ---
    const int j0 = t;
    const int j1 = t + 256;
    const int k0 = j0 >> 7, h0 = j0 & 127;
    const int h1i = (j1 < 384) ? (j1 - 256) : (j1 - 384);
    const float* wt0 = WT + (size_t)j0 * DD;
    const float* wt1 = WT + (size_t)j1 * DD;
    const float bb0 = b_ord[k0 * HH + h0];
    const float bb1 = (j1 < 384) ? b_ord[2 * HH + h1i] : b_orig[h1i];

    float acc0[8], acc1[8];
#pragma unroll
    for (int n = 0; n < 8; ++n) { acc0[n] = dgs[n] * bb0; acc1[n] = dgs[n] * bb1; }

    for (int i = 0; i < DD; i += 4) {
        const float4 w0v = *reinterpret_cast<const float4*>(wt0 + i);
        const float4 w1v = *reinterpret_cast<const float4*>(wt1 + i);
        float4 xv[8];
#pragma unroll
        for (int n = 0; n < 8; ++n) xv[n] = *reinterpret_cast<const float4*>(&xa[n][i]);
#pragma unroll
        for (int ii = 0; ii < 4; ++ii) {
            const float wa = (&w0v.x)[ii];
            const float wb = (&w1v.x)[ii];
#pragma unroll
            for (int n = 0; n < 8; ++n) {
                const float xs = (&xv[n].x)[ii];
                acc0[n] = fmaf(xs, wa, acc0[n]);
                acc1[n] = fmaf(xs, wb, acc1[n]);
            }
        }
    }
#pragma unroll
    for (int n = 0; n < 8; ++n) {
        yl[n][j0] = fmaxf(acc0[n], 0.0f);
        yl[n][j1] = fmaxf(acc1[n], 0.0f);
    }
    __syncthreads();

    // ---- gating: each wave handles 2 nodes --------------------------------
    const float gma = gamma_p[0];
#pragma unroll
    for (int nn = 0; nn < 2; ++nn) {
        const int n = wv * 2 + nn;
        float s0 = yl[n][lane] * W_gate[lane] + yl[n][64 + lane] * W_gate[64 + lane];
        float s1 = yl[n][128 + lane] * W_gate[128 + lane] + yl[n][192 + lane] * W_gate[192 + lane];
        float s2 = yl[n][256 + lane] * W_gate[256 + lane] + yl[n][320 + lane] * W_gate[320 + lane];
#pragma unroll
        for (int off = 32; off; off >>= 1) {
            s0 += __shfl_xor(s0, off);
            s1 += __shfl_xor(s1, off);
            s2 += __shfl_xor(s2, off);
        }
        s0 += b_gate[0]; s1 += b_gate[1]; s2 += b_gate[2];
        const float mx = fmaxf(s0, fmaxf(s1, s2));
        const float e0 = expf(s0 - mx), e1 = expf(s1 - mx), e2 = expf(s2 - mx);
        const float inv = 1.0f / (e0 + e1 + e2);
        const float g0 = e0 * inv, g1 = e1 * inv, g2 = e2 * inv;
#pragma unroll
        for (int hh = lane; hh < 128; hh += 64) {
            zl[n][hh] = yl[n][384 + hh];  // h_orig
            zl[n][128 + hh] = gma * (g0 * yl[n][hh] + g1 * yl[n][128 + hh] + g2 * yl[n][256 + hh]);
        }
    }
    __syncthreads();

    // ---- MLP layer 1 (transposed W1) ---------------------------------------
    const int j = t & 127;
    const int ng = t >> 7;  // 0 or 1
    const float* w1t = W1T + (size_t)j * 256;
    float a0 = b1[j], a1 = a0, a2 = a0, a3 = a0;
    for (int i = 0; i < 2 * HH; i += 4) {
        const float4 wv1 = *reinterpret_cast<const float4*>(w1t + i);
        const float4 z0 = *reinterpret_cast<const float4*>(&zl[ng + 0][i]);
        const float4 z1 = *reinterpret_cast<const float4*>(&zl[ng + 2][i]);
        const float4 z2 = *reinterpret_cast<const float4*>(&zl[ng + 4][i]);
        const float4 z3 = *reinterpret_cast<const float4*>(&zl[ng + 6][i]);
#pragma unroll
        for (int ii = 0; ii < 4; ++ii) {
            const float w = (&wv1.x)[ii];
            a0 = fmaf((&z0.x)[ii], w, a0);
            a1 = fmaf((&z1.x)[ii], w, a1);
            a2 = fmaf((&z2.x)[ii], w, a2);
            a3 = fmaf((&z3.x)[ii], w, a3);
        }
    }
    h1l[ng + 0][j] = fmaxf(a0, 0.0f);
    h1l[ng + 2][j] = fmaxf(a1, 0.0f);
    h1l[ng + 4][j] = fmaxf(a2, 0.0f);
    h1l[ng + 6][j] = fmaxf(a3, 0.0f);
    __syncthreads();

    // ---- output layer (f32 store) ------------------------------------------
    const int g = t >> 5, l32 = t & 31;
    float p0 = 0.0f, p1 = 0.0f;
#pragma unroll
    for (int h = 0; h < 4; ++h) {
        const int idx = l32 + h * 32;
        const float v = h1l[g][idx];
        p0 = fmaf(v, W2[idx * 2 + 0], p0);
        p1 = fmaf(v, W2[idx * 2 + 1], p1);
    }
#pragma unroll
    for (int off = 16; off; off >>= 1) {
        p0 += __shfl_xor(p0, off);
        p1 += __shfl_xor(p1, off);
    }
    if (l32 == 0 && (n0 + g) < N) {
        const size_t o = (size_t)(n0 + g) * 2;
        out[o + 0] = p0 + b2[0];
        out[o + 1] = p1 + b2[1];
    }
}

// ---------------------------------------------------------------------------
extern "C" void kernel_launch(void* const* d_in, const int* in_sizes, int n_in,
                              void* d_out, int out_size, void* d_ws, size_t ws_size,
                              hipStream_t stream) {
    const float* x      = (const float*)d_in[0];
    const int*   ei     = (const int*)d_in[1];
    const float* W_ord  = (const float*)d_in[2];
    const float* b_ord  = (const float*)d_in[3];
    const float* W_gate = (const float*)d_in[4];
    const float* b_gate = (const float*)d_in[5];
    const float* W_orig = (const float*)d_in[6];
    const float* b_orig = (const float*)d_in[7];
    const float* W1     = (const float*)d_in[8];
    const float* b1     = (const float*)d_in[9];
    const float* W2     = (const float*)d_in[10];
    const float* b2     = (const float*)d_in[11];
    const float* gamma  = (const float*)d_in[12];
    float* out = (float*)d_out;

    const int N = in_sizes[0] / DD;
    const int E = in_sizes[1] / 2;

    // ws layout: [deg_i N][cursor N][offs N+1][csr E][align 256][WT 512*256][W1T 128*256]
    int* deg_i  = (int*)d_ws;
    int* cursor = deg_i + N;
    int* offs   = cursor + N;
    int* csr    = offs + (N + 1);
    const size_t int_bytes = (size_t)(2 * N + N + 1 + E) * sizeof(int);
    const size_t wt_off = (int_bytes + 255) & ~(size_t)255;
    float* WT  = (float*)((char*)d_ws + wt_off);
    float* W1T = WT + (size_t)512 * DD;

    hipMemsetAsync(deg_i, 0, (size_t)N * sizeof(int), stream);

    const int eblocks = (E + 255) / 256;
    hogrl_hist<<<eblocks, 256, 0, stream>>>(ei, deg_i, E, N);
    hogrl_scan<<<1, 1024, 0, stream>>>(deg_i, offs, cursor, N);
    hogrl_fill<<<eblocks, 256, 0, stream>>>(ei, cursor, csr, E, N);
    hogrl_wprep<<<640, 256, 0, stream>>>(W_ord, W_orig, W1, WT, W1T);

    const int nblocks = (N + 7) / 8;
    hogrl_node<<<nblocks, 256, 0, stream>>>(offs, csr, x, WT, b_ord, W_gate, b_gate,
                                            b_orig, W1T, b1, W2, b2, gamma, out, N);
}

// Round 8
// 525.482 us; speedup vs baseline: 1.5923x; 1.5923x over previous
//
#include <hip/hip_runtime.h>
#include <hip/hip_bf16.h>

#define DD 256   // feature dim
#define HH 128   // hidden dim

// ---------------------------------------------------------------------------
// CSR build, step 1: degree histogram. One thread per edge.
// int32/int64 probe: int64 values < 2^31 have all-zero odd 32-bit words.
// ---------------------------------------------------------------------------
__global__ __launch_bounds__(256) void hogrl_hist(
    const int* __restrict__ ei, int* __restrict__ deg_i, int E, int N)
{
    __shared__ int sh_is64;
    if (threadIdx.x == 0) {
        int probe = 0;
#pragma unroll
        for (int k = 1; k < 32; k += 2) probe |= ei[k];
        sh_is64 = (probe == 0);
    }
    __syncthreads();
    const int e = blockIdx.x * 256 + threadIdx.x;
    if (e >= E) return;
    int r;
    if (sh_is64) r = (int)((const long long*)ei)[e];
    else         r = ei[e];
    if ((unsigned)r < (unsigned)N) atomicAdd(&deg_i[r], 1);
}

// ---------------------------------------------------------------------------
// CSR build, step 2: exclusive prefix sum (single block, 1024 threads).
// Pre-fills cursor[] with offsets so fill's atomic yields an absolute slot.
// ---------------------------------------------------------------------------
__global__ __launch_bounds__(1024) void hogrl_scan(
    const int* __restrict__ deg_i, int* __restrict__ offs,
    int* __restrict__ cursor, int N)
{
    __shared__ int s[1024];
    const int t = threadIdx.x;
    const int chunk = (N + 1023) / 1024;
    const int lo = min(t * chunk, N), hi = min(lo + chunk, N);
    int sum = 0;
    for (int i = lo; i < hi; ++i) sum += deg_i[i];
    s[t] = sum;
    __syncthreads();
    for (int off = 1; off < 1024; off <<= 1) {
        const int v = (t >= off) ? s[t - off] : 0;
        __syncthreads();
        s[t] += v;
        __syncthreads();
    }
    int run = (t == 0) ? 0 : s[t - 1];
    for (int i = lo; i < hi; ++i) {
        offs[i] = run;
        cursor[i] = run;
        run += deg_i[i];
    }
    if (t == 1023) offs[N] = s[1023];
}

// ---------------------------------------------------------------------------
// CSR build, step 3: fill column lists. cursor holds absolute slots.
// ---------------------------------------------------------------------------
__global__ __launch_bounds__(256) void hogrl_fill(
    const int* __restrict__ ei, int* __restrict__ cursor,
    int* __restrict__ csr, int E, int N)
{
    __shared__ int sh_is64;
    if (threadIdx.x == 0) {
        int probe = 0;
#pragma unroll
        for (int k = 1; k < 32; k += 2) probe |= ei[k];
        sh_is64 = (probe == 0);
    }
    __syncthreads();
    const int e = blockIdx.x * 256 + threadIdx.x;
    if (e >= E) return;
    int r, c;
    if (sh_is64) {
        const long long* e64 = (const long long*)ei;
        r = (int)e64[e];
        c = (int)e64[(size_t)E + e];
    } else {
        r = ei[e];
        c = ei[E + e];
    }
    if ((unsigned)r >= (unsigned)N || (unsigned)c >= (unsigned)N) return;
    const int slot = atomicAdd(&cursor[r], 1);
    csr[slot] = c;
}

// ---------------------------------------------------------------------------
// Fused node kernel: CSR gather (registers) + GEMM (round-6 coalesced W
// access: lane l of a wave reads adjacent columns -> one 256B transaction)
// + gating + MLP + output. 8 nodes per 256-thread block.
//
// LDS phase-overlap: xa (8KB) dies after the GEMM -> zl aliases it.
//                    yl (16KB) dies after gating  -> h1l aliases it.
// 24.6KB total -> 6 blocks/CU (was 37.4KB -> 4).
// ---------------------------------------------------------------------------
__global__ __launch_bounds__(256) void hogrl_node(
    const int* __restrict__ offs, const int* __restrict__ csr,
    const float* __restrict__ x,
    const float* __restrict__ W_ord, const float* __restrict__ b_ord,
    const float* __restrict__ W_gate, const float* __restrict__ b_gate,
    const float* __restrict__ W_orig, const float* __restrict__ b_orig,
    const float* __restrict__ W1, const float* __restrict__ b1,
    const float* __restrict__ W2, const float* __restrict__ b2,
    const float* __restrict__ gamma_p,
    float* __restrict__ out, int N)
{
    __shared__ __align__(16) char smem_raw[8192 + 16384];
    float (*xa)[DD]      = reinterpret_cast<float (*)[DD]>(smem_raw);          // phase 1-2
    float (*yl)[512]     = reinterpret_cast<float (*)[512]>(smem_raw + 8192);  // phase 2-3
    float (*zl)[2 * HH]  = reinterpret_cast<float (*)[2 * HH]>(smem_raw);      // phase 3-4 (aliases xa)
    float (*h1l)[HH]     = reinterpret_cast<float (*)[HH]>(smem_raw + 8192);   // phase 4-5 (aliases yl)
    __shared__ float dgs[8];

    const int t  = threadIdx.x;
    const int n0 = blockIdx.x * 8;
    const int lane = t & 63;
    const int wv = t >> 6;

    // ---- phase 1: CSR gather, wave wv accumulates nodes wv*2, wv*2+1 ------
#pragma unroll
    for (int nn = 0; nn < 2; ++nn) {
        const int k = wv * 2 + nn;
        const int node = n0 + k;
        float4 acc = make_float4(0.f, 0.f, 0.f, 0.f);
        int degn = 0;
        if (node < N) {
            const int s0 = offs[node], e0 = offs[node + 1];
            degn = e0 - s0;
            int i = s0;
            for (; i + 4 <= e0; i += 4) {
                const int c0 = csr[i + 0], c1 = csr[i + 1];
                const int c2 = csr[i + 2], c3 = csr[i + 3];
                const float4 v0 = *reinterpret_cast<const float4*>(x + (size_t)c0 * DD + lane * 4);
                const float4 v1 = *reinterpret_cast<const float4*>(x + (size_t)c1 * DD + lane * 4);
                const float4 v2 = *reinterpret_cast<const float4*>(x + (size_t)c2 * DD + lane * 4);
                const float4 v3 = *reinterpret_cast<const float4*>(x + (size_t)c3 * DD + lane * 4);
                acc.x += v0.x + v1.x + v2.x + v3.x;
                acc.y += v0.y + v1.y + v2.y + v3.y;
                acc.z += v0.z + v1.z + v2.z + v3.z;
                acc.w += v0.w + v1.w + v2.w + v3.w;
            }
            for (; i < e0; ++i) {
                const int c = csr[i];
                const float4 v = *reinterpret_cast<const float4*>(x + (size_t)c * DD + lane * 4);
                acc.x += v.x; acc.y += v.y; acc.z += v.z; acc.w += v.w;
            }
        }
        *reinterpret_cast<float4*>(&xa[k][lane * 4]) = acc;
        if (lane == 0) dgs[k] = (float)degn;
    }
    __syncthreads();

    // ---- phase 2: fused 256x512 GEMM (coalesced per-wave W reads) ---------
    const int j0 = t;
    const int j1 = t + 256;
    const int k0 = j0 >> 7, h0 = j0 & 127;
    const int h1i = (j1 < 384) ? (j1 - 256) : (j1 - 384);
    const float* wp0 = W_ord + (size_t)k0 * DD * HH + h0;
    const float* wp1 = (j1 < 384) ? (W_ord + 2 * DD * HH + h1i) : (W_orig + h1i);
    const float bb0 = b_ord[k0 * HH + h0];
    const float bb1 = (j1 < 384) ? b_ord[2 * HH + h1i] : b_orig[h1i];

    float acc0[8], acc1[8];
#pragma unroll
    for (int n = 0; n < 8; ++n) { acc0[n] = dgs[n] * bb0; acc1[n] = dgs[n] * bb1; }

    for (int i = 0; i < DD; i += 4) {
        float4 xv[8];
#pragma unroll
        for (int n = 0; n < 8; ++n) xv[n] = *reinterpret_cast<const float4*>(&xa[n][i]);
#pragma unroll
        for (int ii = 0; ii < 4; ++ii) {
            const float wa = wp0[(i + ii) * HH];
            const float wb = wp1[(i + ii) * HH];
#pragma unroll
            for (int n = 0; n < 8; ++n) {
                const float xs = (&xv[n].x)[ii];
                acc0[n] = fmaf(xs, wa, acc0[n]);
                acc1[n] = fmaf(xs, wb, acc1[n]);
            }
        }
    }
#pragma unroll
    for (int n = 0; n < 8; ++n) {
        yl[n][j0] = fmaxf(acc0[n], 0.0f);
        yl[n][j1] = fmaxf(acc1[n], 0.0f);
    }
    __syncthreads();   // xa dead; zl (alias of xa) comes alive below

    // ---- phase 3: gating, each wave handles 2 nodes -----------------------
    const float gma = gamma_p[0];
#pragma unroll
    for (int nn = 0; nn < 2; ++nn) {
        const int n = wv * 2 + nn;
        float s0 = yl[n][lane] * W_gate[lane] + yl[n][64 + lane] * W_gate[64 + lane];
        float s1 = yl[n][128 + lane] * W_gate[128 + lane] + yl[n][192 + lane] * W_gate[192 + lane];
        float s2 = yl[n][256 + lane] * W_gate[256 + lane] + yl[n][320 + lane] * W_gate[320 + lane];
#pragma unroll
        for (int off = 32; off; off >>= 1) {
            s0 += __shfl_xor(s0, off);
            s1 += __shfl_xor(s1, off);
            s2 += __shfl_xor(s2, off);
        }
        s0 += b_gate[0]; s1 += b_gate[1]; s2 += b_gate[2];
        const float mx = fmaxf(s0, fmaxf(s1, s2));
        const float e0 = expf(s0 - mx), e1 = expf(s1 - mx), e2 = expf(s2 - mx);
        const float inv = 1.0f / (e0 + e1 + e2);
        const float g0 = e0 * inv, g1 = e1 * inv, g2 = e2 * inv;
#pragma unroll
        for (int hh = lane; hh < 128; hh += 64) {
            zl[n][hh] = yl[n][384 + hh];  // h_orig
            zl[n][128 + hh] = gma * (g0 * yl[n][hh] + g1 * yl[n][128 + hh] + g2 * yl[n][256 + hh]);
        }
    }
    __syncthreads();   // yl dead; h1l (alias of yl) comes alive below

    // ---- phase 4: MLP layer 1 ---------------------------------------------
    const int j = t & 127;
    const int ng = t >> 7;  // 0 or 1
    float a0 = b1[j], a1 = a0, a2 = a0, a3 = a0;
    for (int i = 0; i < 2 * HH; i += 4) {
        const float4 z0 = *reinterpret_cast<const float4*>(&zl[ng + 0][i]);
        const float4 z1 = *reinterpret_cast<const float4*>(&zl[ng + 2][i]);
        const float4 z2 = *reinterpret_cast<const float4*>(&zl[ng + 4][i]);
        const float4 z3 = *reinterpret_cast<const float4*>(&zl[ng + 6][i]);
#pragma unroll
        for (int ii = 0; ii < 4; ++ii) {
            const float wv1 = W1[(i + ii) * HH + j];
            a0 = fmaf((&z0.x)[ii], wv1, a0);
            a1 = fmaf((&z1.x)[ii], wv1, a1);
            a2 = fmaf((&z2.x)[ii], wv1, a2);
            a3 = fmaf((&z3.x)[ii], wv1, a3);
        }
    }
    __syncthreads();   // everyone done READING zl before h1l overwrite races? no:
                       // h1l aliases yl, zl aliases xa -> no overlap; but keep the
                       // barrier so all zl reads precede phase-5's h1l reads ordering
    h1l[ng + 0][j] = fmaxf(a0, 0.0f);
    h1l[ng + 2][j] = fmaxf(a1, 0.0f);
    h1l[ng + 4][j] = fmaxf(a2, 0.0f);
    h1l[ng + 6][j] = fmaxf(a3, 0.0f);
    __syncthreads();

    // ---- phase 5: output layer (f32 store) --------------------------------
    const int g = t >> 5, l32 = t & 31;
    float p0 = 0.0f, p1 = 0.0f;
#pragma unroll
    for (int h = 0; h < 4; ++h) {
        const int idx = l32 + h * 32;
        const float v = h1l[g][idx];
        p0 = fmaf(v, W2[idx * 2 + 0], p0);
        p1 = fmaf(v, W2[idx * 2 + 1], p1);
    }
#pragma unroll
    for (int off = 16; off; off >>= 1) {
        p0 += __shfl_xor(p0, off);
        p1 += __shfl_xor(p1, off);
    }
    if (l32 == 0 && (n0 + g) < N) {
        const size_t o = (size_t)(n0 + g) * 2;
        out[o + 0] = p0 + b2[0];
        out[o + 1] = p1 + b2[1];
    }
}

// ---------------------------------------------------------------------------
extern "C" void kernel_launch(void* const* d_in, const int* in_sizes, int n_in,
                              void* d_out, int out_size, void* d_ws, size_t ws_size,
                              hipStream_t stream) {
    const float* x      = (const float*)d_in[0];
    const int*   ei     = (const int*)d_in[1];
    const float* W_ord  = (const float*)d_in[2];
    const float* b_ord  = (const float*)d_in[3];
    const float* W_gate = (const float*)d_in[4];
    const float* b_gate = (const float*)d_in[5];
    const float* W_orig = (const float*)d_in[6];
    const float* b_orig = (const float*)d_in[7];
    const float* W1     = (const float*)d_in[8];
    const float* b1     = (const float*)d_in[9];
    const float* W2     = (const float*)d_in[10];
    const float* b2     = (const float*)d_in[11];
    const float* gamma  = (const float*)d_in[12];
    float* out = (float*)d_out;

    const int N = in_sizes[0] / DD;
    const int E = in_sizes[1] / 2;

    // ws layout: [deg_i N][cursor N][offs N+1][csr E]
    int* deg_i  = (int*)d_ws;
    int* cursor = deg_i + N;
    int* offs   = cursor + N;
    int* csr    = offs + (N + 1);

    hipMemsetAsync(deg_i, 0, (size_t)N * sizeof(int), stream);

    const int eblocks = (E + 255) / 256;
    hogrl_hist<<<eblocks, 256, 0, stream>>>(ei, deg_i, E, N);
    hogrl_scan<<<1, 1024, 0, stream>>>(deg_i, offs, cursor, N);
    hogrl_fill<<<eblocks, 256, 0, stream>>>(ei, cursor, csr, E, N);

    const int nblocks = (N + 7) / 8;
    hogrl_node<<<nblocks, 256, 0, stream>>>(offs, csr, x, W_ord, b_ord, W_gate, b_gate,
                                            W_orig, b_orig, W1, b1, W2, b2, gamma, out, N);
}

// Round 9
// 436.511 us; speedup vs baseline: 1.9169x; 1.2038x over previous
//
#include <hip/hip_runtime.h>
#include <hip/hip_bf16.h>

#define DD 256   // feature dim
#define HH 128   // hidden dim
#define NB 16    // nodes per block

typedef __attribute__((ext_vector_type(8))) short bf16x8;
typedef __attribute__((ext_vector_type(4))) float f32x4v;

// ---------------------------------------------------------------------------
// f32 -> bf16 hi/lo split (RNE). x ≈ hi + lo with ~17 mantissa bits kept.
// ---------------------------------------------------------------------------
__device__ __forceinline__ void bf16split(float x, short& hi, short& lo) {
    union { float f; unsigned u; } a; a.f = x;
    unsigned rh = a.u + 0x7fffu + ((a.u >> 16) & 1u);
    hi = (short)(rh >> 16);
    union { unsigned u; float f; } hf; hf.u = ((unsigned)(unsigned short)hi) << 16;
    float r = x - hf.f;
    union { float f; unsigned u; } c; c.f = r;
    unsigned rl = c.u + 0x7fffu + ((c.u >> 16) & 1u);
    lo = (short)(rl >> 16);
}

// ---------------------------------------------------------------------------
// CSR build (unchanged from round 8 — known good).
// ---------------------------------------------------------------------------
__global__ __launch_bounds__(256) void hogrl_hist(
    const int* __restrict__ ei, int* __restrict__ deg_i, int E, int N)
{
    __shared__ int sh_is64;
    if (threadIdx.x == 0) {
        int probe = 0;
#pragma unroll
        for (int k = 1; k < 32; k += 2) probe |= ei[k];
        sh_is64 = (probe == 0);
    }
    __syncthreads();
    const int e = blockIdx.x * 256 + threadIdx.x;
    if (e >= E) return;
    int r;
    if (sh_is64) r = (int)((const long long*)ei)[e];
    else         r = ei[e];
    if ((unsigned)r < (unsigned)N) atomicAdd(&deg_i[r], 1);
}

__global__ __launch_bounds__(1024) void hogrl_scan(
    const int* __restrict__ deg_i, int* __restrict__ offs,
    int* __restrict__ cursor, int N)
{
    __shared__ int s[1024];
    const int t = threadIdx.x;
    const int chunk = (N + 1023) / 1024;
    const int lo = min(t * chunk, N), hi = min(lo + chunk, N);
    int sum = 0;
    for (int i = lo; i < hi; ++i) sum += deg_i[i];
    s[t] = sum;
    __syncthreads();
    for (int off = 1; off < 1024; off <<= 1) {
        const int v = (t >= off) ? s[t - off] : 0;
        __syncthreads();
        s[t] += v;
        __syncthreads();
    }
    int run = (t == 0) ? 0 : s[t - 1];
    for (int i = lo; i < hi; ++i) {
        offs[i] = run;
        cursor[i] = run;
        run += deg_i[i];
    }
    if (t == 1023) offs[N] = s[1023];
}

__global__ __launch_bounds__(256) void hogrl_fill(
    const int* __restrict__ ei, int* __restrict__ cursor,
    int* __restrict__ csr, int E, int N)
{
    __shared__ int sh_is64;
    if (threadIdx.x == 0) {
        int probe = 0;
#pragma unroll
        for (int k = 1; k < 32; k += 2) probe |= ei[k];
        sh_is64 = (probe == 0);
    }
    __syncthreads();
    const int e = blockIdx.x * 256 + threadIdx.x;
    if (e >= E) return;
    int r, c;
    if (sh_is64) {
        const long long* e64 = (const long long*)ei;
        r = (int)e64[e];
        c = (int)e64[(size_t)E + e];
    } else {
        r = ei[e];
        c = ei[E + e];
    }
    if ((unsigned)r >= (unsigned)N || (unsigned)c >= (unsigned)N) return;
    const int slot = atomicAdd(&cursor[r], 1);
    csr[slot] = c;
}

// ---------------------------------------------------------------------------
// Weight fragment prep (once): pack W_cat = [W_ord0|W_ord1|W_ord2|W_orig]
// (256 x 512) into MFMA B-fragment order, bf16 hi/lo.
// B-frag for 16x16x32: lane l holds col n = nt*16 + (l&15),
//                      k = kt*32 + 8*(l>>4) + j  (j = 0..7).
// Wf[hi/lo][((nt*8+kt)*64 + l)*8 + j]  -> per-wave 16B/lane coalesced loads.
// ---------------------------------------------------------------------------
__global__ __launch_bounds__(256) void hogrl_wprep(
    const float* __restrict__ W_ord, const float* __restrict__ W_orig,
    short* __restrict__ wfh, short* __restrict__ wfl)
{
    const int id = blockIdx.x * 256 + threadIdx.x;   // 16384 total
    const int l  = id & 63;
    const int kt = (id >> 6) & 7;
    const int nt = id >> 9;
    const int n  = nt * 16 + (l & 15);
    const int k0 = kt * 32 + (l >> 4) * 8;
    bf16x8 h8, l8;
#pragma unroll
    for (int j = 0; j < 8; ++j) {
        const int k = k0 + j;
        float w;
        if (n < 384) w = W_ord[(size_t)(n >> 7) * DD * HH + (size_t)k * HH + (n & 127)];
        else         w = W_orig[(size_t)k * HH + (n - 384)];
        short hh, ll;
        bf16split(w, hh, ll);
        h8[j] = hh; l8[j] = ll;
    }
    const size_t base = ((size_t)(nt * 8 + kt) * 64 + l) * 8;
    *(bf16x8*)(wfh + base) = h8;
    *(bf16x8*)(wfl + base) = l8;
}

// ---------------------------------------------------------------------------
// Fused node kernel: 16 nodes / 512 threads (8 waves).
//   phase 1: CSR gather (2 nodes/wave) -> xa[16][260] f32 (padded)
//   phase 2: A-frag cvt to bf16 hi/lo regs; barrier; MFMA 16x512 GEMM
//            (4 N-tiles/wave x 8 K x 3 split-MFMAs), bias+relu -> yl[16][516]
//   phase 3: softmax gating -> zl[16][256]
//   phase 4: scalar MLP1 (256->128) -> h1[16][128]
//   phase 5: output (128->2), f32 store
// LDS aliasing: xa/yl/h1 share [0,33024); zl separate. Total 49.5 KB.
// ---------------------------------------------------------------------------
__global__ __launch_bounds__(512) void hogrl_node(
    const int* __restrict__ offs, const int* __restrict__ csr,
    const float* __restrict__ x,
    const short* __restrict__ wfh, const short* __restrict__ wfl,
    const float* __restrict__ b_ord, const float* __restrict__ b_orig,
    const float* __restrict__ W_gate, const float* __restrict__ b_gate,
    const float* __restrict__ W1, const float* __restrict__ b1,
    const float* __restrict__ W2, const float* __restrict__ b2,
    const float* __restrict__ gamma_p,
    float* __restrict__ out, int N)
{
    __shared__ __align__(16) char smem_raw[33024 + 16384 + 64];
    float* xa  = (float*)smem_raw;              // [16][260], phases 1-2a
    float* yl  = (float*)smem_raw;              // [16][516], phases 2b-3 (aliases xa)
    float* h1  = (float*)smem_raw;              // [16][128], phases 4-5  (aliases yl)
    float* zl  = (float*)(smem_raw + 33024);    // [16][256], phases 3-4
    float* dgs = (float*)(smem_raw + 33024 + 16384);  // [16]

    const int t    = threadIdx.x;
    const int lane = t & 63;
    const int wv   = t >> 6;           // 0..7
    const int n0   = blockIdx.x * NB;

    // ---- phase 1: CSR gather, wave wv -> nodes wv*2, wv*2+1 ---------------
#pragma unroll
    for (int nn = 0; nn < 2; ++nn) {
        const int k = wv * 2 + nn;
        const int node = n0 + k;
        float4 acc = make_float4(0.f, 0.f, 0.f, 0.f);
        int degn = 0;
        if (node < N) {
            const int s0 = offs[node], e0 = offs[node + 1];
            degn = e0 - s0;
            int i = s0;
            for (; i + 4 <= e0; i += 4) {
                const int c0 = csr[i + 0], c1 = csr[i + 1];
                const int c2 = csr[i + 2], c3 = csr[i + 3];
                const float4 v0 = *reinterpret_cast<const float4*>(x + (size_t)c0 * DD + lane * 4);
                const float4 v1 = *reinterpret_cast<const float4*>(x + (size_t)c1 * DD + lane * 4);
                const float4 v2 = *reinterpret_cast<const float4*>(x + (size_t)c2 * DD + lane * 4);
                const float4 v3 = *reinterpret_cast<const float4*>(x + (size_t)c3 * DD + lane * 4);
                acc.x += v0.x + v1.x + v2.x + v3.x;
                acc.y += v0.y + v1.y + v2.y + v3.y;
                acc.z += v0.z + v1.z + v2.z + v3.z;
                acc.w += v0.w + v1.w + v2.w + v3.w;
            }
            for (; i < e0; ++i) {
                const int c = csr[i];
                const float4 v = *reinterpret_cast<const float4*>(x + (size_t)c * DD + lane * 4);
                acc.x += v.x; acc.y += v.y; acc.z += v.z; acc.w += v.w;
            }
        }
        *reinterpret_cast<float4*>(xa + k * 260 + lane * 4) = acc;
        if (lane == 0) dgs[k] = (float)degn;
    }
    __syncthreads();

    // ---- phase 2a: A-fragment preload + bf16 split (registers) ------------
    // A-frag: lane l holds row m = l&15, k = kt*32 + 8*(l>>4) + j.
    const int am = lane & 15, ag = lane >> 4;
    bf16x8 ahi[8], alo[8];
#pragma unroll
    for (int kt = 0; kt < 8; ++kt) {
        const float* src = xa + am * 260 + kt * 32 + ag * 8;
        const f32x4v u0 = *(const f32x4v*)src;
        const f32x4v u1 = *(const f32x4v*)(src + 4);
#pragma unroll
        for (int j = 0; j < 4; ++j) {
            short hh, ll;
            bf16split(u0[j], hh, ll);
            ahi[kt][j] = hh; alo[kt][j] = ll;
            bf16split(u1[j], hh, ll);
            ahi[kt][4 + j] = hh; alo[kt][4 + j] = ll;
        }
    }
    __syncthreads();   // all xa reads done; yl may now overwrite the region

    // ---- phase 2b: MFMA GEMM, wave owns N-tiles wv*4 .. wv*4+3 ------------
    f32x4v accq[4];
#pragma unroll
    for (int q = 0; q < 4; ++q) {
        const int nt = wv * 4 + q;
        f32x4v a = {0.f, 0.f, 0.f, 0.f};
#pragma unroll
        for (int kt = 0; kt < 8; ++kt) {
            const size_t base = ((size_t)(nt * 8 + kt) * 64 + lane) * 8;
            const bf16x8 bh = *(const bf16x8*)(wfh + base);
            const bf16x8 bl = *(const bf16x8*)(wfl + base);
            a = __builtin_amdgcn_mfma_f32_16x16x32_bf16(ahi[kt], bh, a, 0, 0, 0);
            a = __builtin_amdgcn_mfma_f32_16x16x32_bf16(ahi[kt], bl, a, 0, 0, 0);
            a = __builtin_amdgcn_mfma_f32_16x16x32_bf16(alo[kt], bh, a, 0, 0, 0);
        }
        accq[q] = a;
    }
    // epilogue: bias + relu -> yl.  C map: col = lane&15, row = (lane>>4)*4+r.
#pragma unroll
    for (int q = 0; q < 4; ++q) {
        const int col = (wv * 4 + q) * 16 + (lane & 15);
        const float bb = (col < 384) ? b_ord[col] : b_orig[col - 384];
#pragma unroll
        for (int r = 0; r < 4; ++r) {
            const int m = (lane >> 4) * 4 + r;
            const float y = accq[q][r] + dgs[m] * bb;
            yl[m * 516 + col] = fmaxf(y, 0.0f);
        }
    }
    __syncthreads();

    // ---- phase 3: gating, wave wv -> nodes wv*2, wv*2+1 --------------------
    const float gma = gamma_p[0];
#pragma unroll
    for (int nn = 0; nn < 2; ++nn) {
        const int n = wv * 2 + nn;
        const float* yr = yl + n * 516;
        float s0 = yr[lane] * W_gate[lane] + yr[64 + lane] * W_gate[64 + lane];
        float s1 = yr[128 + lane] * W_gate[128 + lane] + yr[192 + lane] * W_gate[192 + lane];
        float s2 = yr[256 + lane] * W_gate[256 + lane] + yr[320 + lane] * W_gate[320 + lane];
#pragma unroll
        for (int off = 32; off; off >>= 1) {
            s0 += __shfl_xor(s0, off);
            s1 += __shfl_xor(s1, off);
            s2 += __shfl_xor(s2, off);
        }
        s0 += b_gate[0]; s1 += b_gate[1]; s2 += b_gate[2];
        const float mx = fmaxf(s0, fmaxf(s1, s2));
        const float e0 = expf(s0 - mx), e1 = expf(s1 - mx), e2 = expf(s2 - mx);
        const float inv = 1.0f / (e0 + e1 + e2);
        const float g0 = e0 * inv, g1 = e1 * inv, g2 = e2 * inv;
#pragma unroll
        for (int hh = lane; hh < 128; hh += 64) {
            zl[n * 256 + hh]       = yr[384 + hh];  // h_orig
            zl[n * 256 + 128 + hh] = gma * (g0 * yr[hh] + g1 * yr[128 + hh] + g2 * yr[256 + hh]);
        }
    }
    __syncthreads();   // yl dead; h1 (alias) comes alive in phase 4

    // ---- phase 4: MLP layer 1 (scalar).  thread: col j, node-group ng ------
    const int j  = t & 127;
    const int ng = t >> 7;     // 0..3 -> nodes ng, ng+4, ng+8, ng+12
    float a0 = b1[j], a1 = a0, a2 = a0, a3 = a0;
    for (int i = 0; i < 2 * HH; i += 4) {
        const float4 z0 = *reinterpret_cast<const float4*>(zl + (ng + 0) * 256 + i);
        const float4 z1 = *reinterpret_cast<const float4*>(zl + (ng + 4) * 256 + i);
        const float4 z2 = *reinterpret_cast<const float4*>(zl + (ng + 8) * 256 + i);
        const float4 z3 = *reinterpret_cast<const float4*>(zl + (ng + 12) * 256 + i);
#pragma unroll
        for (int ii = 0; ii < 4; ++ii) {
            const float wv1 = W1[(i + ii) * HH + j];
            a0 = fmaf((&z0.x)[ii], wv1, a0);
            a1 = fmaf((&z1.x)[ii], wv1, a1);
            a2 = fmaf((&z2.x)[ii], wv1, a2);
            a3 = fmaf((&z3.x)[ii], wv1, a3);
        }
    }
    __syncthreads();   // ensure all zl reads done before... (zl disjoint from h1; order-safety for phase 5)
    h1[(ng + 0)  * 128 + j] = fmaxf(a0, 0.0f);
    h1[(ng + 4)  * 128 + j] = fmaxf(a1, 0.0f);
    h1[(ng + 8)  * 128 + j] = fmaxf(a2, 0.0f);
    h1[(ng + 12) * 128 + j] = fmaxf(a3, 0.0f);
    __syncthreads();

    // ---- phase 5: output layer (f32 store) ---------------------------------
    const int g = t >> 5, l32 = t & 31;   // 16 groups x 32 lanes
    float p0 = 0.0f, p1 = 0.0f;
#pragma unroll
    for (int h = 0; h < 4; ++h) {
        const int idx = l32 + h * 32;
        const float v = h1[g * 128 + idx];
        p0 = fmaf(v, W2[idx * 2 + 0], p0);
        p1 = fmaf(v, W2[idx * 2 + 1], p1);
    }
#pragma unroll
    for (int off = 16; off; off >>= 1) {
        p0 += __shfl_xor(p0, off);
        p1 += __shfl_xor(p1, off);
    }
    if (l32 == 0 && (n0 + g) < N) {
        const size_t o = (size_t)(n0 + g) * 2;
        out[o + 0] = p0 + b2[0];
        out[o + 1] = p1 + b2[1];
    }
}

// ---------------------------------------------------------------------------
extern "C" void kernel_launch(void* const* d_in, const int* in_sizes, int n_in,
                              void* d_out, int out_size, void* d_ws, size_t ws_size,
                              hipStream_t stream) {
    const float* x      = (const float*)d_in[0];
    const int*   ei     = (const int*)d_in[1];
    const float* W_ord  = (const float*)d_in[2];
    const float* b_ord  = (const float*)d_in[3];
    const float* W_gate = (const float*)d_in[4];
    const float* b_gate = (const float*)d_in[5];
    const float* W_orig = (const float*)d_in[6];
    const float* b_orig = (const float*)d_in[7];
    const float* W1     = (const float*)d_in[8];
    const float* b1     = (const float*)d_in[9];
    const float* W2     = (const float*)d_in[10];
    const float* b2     = (const float*)d_in[11];
    const float* gamma  = (const float*)d_in[12];
    float* out = (float*)d_out;

    const int N = in_sizes[0] / DD;
    const int E = in_sizes[1] / 2;

    // ws: [deg_i N][cursor N][offs N+1][csr E][align 256][wfh 128Ki short][wfl 128Ki short]
    int* deg_i  = (int*)d_ws;
    int* cursor = deg_i + N;
    int* offs   = cursor + N;
    int* csr    = offs + (N + 1);
    const size_t int_bytes = (size_t)(3 * N + 1 + E) * sizeof(int);
    const size_t woff = (int_bytes + 255) & ~(size_t)255;
    short* wfh = (short*)((char*)d_ws + woff);
    short* wfl = wfh + (size_t)32 * 8 * 64 * 8;

    hipMemsetAsync(deg_i, 0, (size_t)N * sizeof(int), stream);

    const int eblocks = (E + 255) / 256;
    hogrl_hist<<<eblocks, 256, 0, stream>>>(ei, deg_i, E, N);
    hogrl_scan<<<1, 1024, 0, stream>>>(deg_i, offs, cursor, N);
    hogrl_fill<<<eblocks, 256, 0, stream>>>(ei, cursor, csr, E, N);
    hogrl_wprep<<<64, 256, 0, stream>>>(W_ord, W_orig, wfh, wfl);

    const int nblocks = (N + NB - 1) / NB;
    hogrl_node<<<nblocks, 512, 0, stream>>>(offs, csr, x, wfh, wfl, b_ord, b_orig,
                                            W_gate, b_gate, W1, b1, W2, b2, gamma, out, N);
}